// Round 9
// baseline (223.258 us; speedup 1.0000x reference)
//
#include <hip/hip_runtime.h>

#define NMS_TH 0.7

__device__ __forceinline__ unsigned long long readlane64(unsigned long long x,
                                                         int l) {
    unsigned int lo = __builtin_amdgcn_readlane((unsigned int)x, l);
    unsigned int hi = __builtin_amdgcn_readlane((unsigned int)(x >> 32), l);
    return ((unsigned long long)hi << 32) | lo;
}

// ---------------------------------------------------------------------------
// Kernel A: fp64 corners + fp32 corners + fp64 areas + packed fp32 AABB.
// Also zeroes the fused kernel's done-counter (re-done every launch).
// ---------------------------------------------------------------------------
__global__ void corners_kernel(const float* __restrict__ boxes,
                               double* __restrict__ cor,    // N*8 fp64
                               float* __restrict__ cor32,   // N*8 fp32
                               double* __restrict__ areas,  // N fp64
                               float4* __restrict__ aabb4,  // N
                               float* __restrict__ areaf,   // N fp32
                               unsigned int* __restrict__ done,
                               int N) {
    int i = blockIdx.x * blockDim.x + threadIdx.x;
    if (blockIdx.x == 0 && threadIdx.x == 0) *done = 0u;
    if (i >= N) return;
    double xc = boxes[i * 5 + 0];
    double yc = boxes[i * 5 + 1];
    double w  = boxes[i * 5 + 2];
    double h  = boxes[i * 5 + 3];
    double t  = boxes[i * 5 + 4];
    double th = t * 0.017453292519943295;  // pi/180
    double c = cos(th), s = sin(th);
    const double lx[4] = {0.5, -0.5, -0.5, 0.5};
    const double ly[4] = {0.5, 0.5, -0.5, -0.5};
    double xmn = 1e30, xmx = -1e30, ymn = 1e30, ymx = -1e30;
#pragma unroll
    for (int k = 0; k < 4; ++k) {
        double x = xc + lx[k] * w * c - ly[k] * h * s;
        double y = yc + lx[k] * w * s + ly[k] * h * c;
        cor[i * 8 + k * 2 + 0] = x;
        cor[i * 8 + k * 2 + 1] = y;
        cor32[i * 8 + k * 2 + 0] = (float)x;
        cor32[i * 8 + k * 2 + 1] = (float)y;
        xmn = fmin(xmn, x); xmx = fmax(xmx, x);
        ymn = fmin(ymn, y); ymx = fmax(ymx, y);
    }
    areas[i] = w * h;
    aabb4[i] = make_float4((float)xmn, (float)xmx, (float)ymn, (float)ymx);
    areaf[i] = (float)(w * h);
}

// ---------------------------------------------------------------------------
// Convex-quad intersection area via Green's theorem — fp64 exact version.
// ---------------------------------------------------------------------------
__device__ __forceinline__ double clip_sum(const double* __restrict__ px,
                                           const double* __restrict__ py,
                                           const double* __restrict__ qx,
                                           const double* __restrict__ qy) {
    double acc = 0.0;
#pragma unroll
    for (int e = 0; e < 4; ++e) {
        double x0 = px[e], y0 = py[e];
        double x1 = px[(e + 1) & 3], y1 = py[(e + 1) & 3];
        double dx = x1 - x0, dy = y1 - y0;
        double t0 = 0.0, t1 = 1.0;
        bool empty = false;
#pragma unroll
        for (int f = 0; f < 4; ++f) {
            double ex0 = qx[f], ey0 = qy[f];
            double ex1 = qx[(f + 1) & 3], ey1 = qy[(f + 1) & 3];
            double edx = ex1 - ex0, edy = ey1 - ey0;
            double f0 = edx * (y0 - ey0) - edy * (x0 - ex0);
            double f1 = edx * (y1 - ey0) - edy * (x1 - ex0);
            double df = f1 - f0;
            if (df > 0.0) {
                t0 = fmax(t0, -f0 / df);
            } else if (df < 0.0) {
                t1 = fmin(t1, -f0 / df);
            } else if (f0 < 0.0) {
                empty = true;
            }
        }
        if (!empty && t0 < t1) {
            double ax = x0 + t0 * dx, ay = y0 + t0 * dy;
            double bx = x0 + t1 * dx, by = y0 + t1 * dy;
            acc += ax * by - bx * ay;
        }
    }
    return acc;
}

__device__ __forceinline__ bool exact_suppress64(const double* __restrict__ cor,
                                                 const double* __restrict__ areas,
                                                 int i, int j) {
    double px[4], py[4], qx[4], qy[4];
#pragma unroll
    for (int k = 0; k < 4; ++k) {
        px[k] = cor[i * 8 + k * 2 + 0];
        py[k] = cor[i * 8 + k * 2 + 1];
        qx[k] = cor[j * 8 + k * 2 + 0];
        qy[k] = cor[j * 8 + k * 2 + 1];
    }
    double inter = 0.5 * (clip_sum(px, py, qx, qy) + clip_sum(qx, qy, px, py));
    inter = fmax(inter, 0.0);
    double uni = areas[i] + areas[j] - inter;
    double iou = inter / fmax(uni, 1e-8);
    return iou > NMS_TH;
}

// ---------------------------------------------------------------------------
// fp32 fast-path clip (hardware rcp, ~1 ulp — inside the decision band).
// ---------------------------------------------------------------------------
__device__ __forceinline__ float clip_sum_f32(const float* __restrict__ px,
                                              const float* __restrict__ py,
                                              const float* __restrict__ qx,
                                              const float* __restrict__ qy) {
    float acc = 0.0f;
#pragma unroll
    for (int e = 0; e < 4; ++e) {
        float x0 = px[e], y0 = py[e];
        float x1 = px[(e + 1) & 3], y1 = py[(e + 1) & 3];
        float dx = x1 - x0, dy = y1 - y0;
        float t0 = 0.0f, t1 = 1.0f;
        bool empty = false;
#pragma unroll
        for (int f = 0; f < 4; ++f) {
            float ex0 = qx[f], ey0 = qy[f];
            float ex1 = qx[(f + 1) & 3], ey1 = qy[(f + 1) & 3];
            float edx = ex1 - ex0, edy = ey1 - ey0;
            float f0 = edx * (y0 - ey0) - edy * (x0 - ex0);
            float f1 = edx * (y1 - ey0) - edy * (x1 - ex0);
            float df = f1 - f0;
            if (df > 0.0f) {
                t0 = fmaxf(t0, -f0 * __builtin_amdgcn_rcpf(df));
            } else if (df < 0.0f) {
                t1 = fminf(t1, -f0 * __builtin_amdgcn_rcpf(df));
            } else if (f0 < 0.0f) {
                empty = true;
            }
        }
        if (!empty && t0 < t1) {
            float ax = x0 + t0 * dx, ay = y0 + t0 * dy;
            float bx = x0 + t1 * dx, by = y0 + t1 * dy;
            acc += ax * by - bx * ay;
        }
    }
    return acc;
}

// ---------------------------------------------------------------------------
// Greedy sweep (device fn, runs on ONE wave: threads 0..63 of the last
// block).  Edge-list algorithm, no global loads on the serial chain except
// the rare cnt>6 mask-row fallback.  dm (current chunk's removed word) is
// maintained in scalar registers — inline-target updates hit it directly,
// avoiding a readlane64 round-trip per kept row.
// Requires N <= 2048; mask stride fixed at 32 words.
// ---------------------------------------------------------------------------
__device__ void greedy_sweep(const unsigned long long* __restrict__ mask,
                             const unsigned long long* __restrict__ rowinfo,
                             int* __restrict__ out, int N, int topn) {
    constexpr int WORDS = 32;
    int lane = threadIdx.x;  // 0..63
    unsigned long long removed = 0ULL;

    unsigned long long ri0[WORDS], ri1[WORDS];
    const ulonglong2* rv = (const ulonglong2*)rowinfo;
#pragma unroll
    for (int c = 0; c < WORDS; ++c) {
        int r = c * 64 + lane;
        if (r < N) {
            ulonglong2 v = rv[r];
            ri0[c] = v.x;
            ri1[c] = v.y;
        } else {
            ri0[c] = 0ULL;
            ri1[c] = 0ULL;
        }
    }

#pragma unroll
    for (int c = 0; c < WORDS; ++c) {
        unsigned long long bits = __ballot((ri0[c] & 0xffffULL) != 0ULL);
        if (!bits) continue;
        unsigned long long dm = readlane64(removed, c);  // scalar copy
        unsigned long long todo = bits;
        for (;;) {
            unsigned long long bb = todo & ~dm;
            if (!bb) break;
            int b = __builtin_amdgcn_readfirstlane(__ffsll(bb) - 1);
            todo &= ~(1ULL << b);
            unsigned long long i0 = readlane64(ri0[c], b);
            int cnt = (int)(i0 & 0xffffULL);
            {
                int t0 = (int)((i0 >> 16) & 0xffffULL);
                if (lane == (t0 >> 6)) removed |= 1ULL << (t0 & 63);
                if ((t0 >> 6) == c) dm |= 1ULL << (t0 & 63);
            }
            if (cnt >= 2) {
                int t1 = (int)((i0 >> 32) & 0xffffULL);
                if (lane == (t1 >> 6)) removed |= 1ULL << (t1 & 63);
                if ((t1 >> 6) == c) dm |= 1ULL << (t1 & 63);
            }
            if (cnt >= 3) {
                int t2 = (int)((i0 >> 48) & 0xffffULL);
                if (lane == (t2 >> 6)) removed |= 1ULL << (t2 & 63);
                if ((t2 >> 6) == c) dm |= 1ULL << (t2 & 63);
            }
            if (cnt >= 4) {
                if (cnt <= 6) {
                    unsigned long long i1 = readlane64(ri1[c], b);
                    int t3 = (int)(i1 & 0xffffULL);
                    if (lane == (t3 >> 6)) removed |= 1ULL << (t3 & 63);
                    if ((t3 >> 6) == c) dm |= 1ULL << (t3 & 63);
                    if (cnt >= 5) {
                        int t4 = (int)((i1 >> 16) & 0xffffULL);
                        if (lane == (t4 >> 6)) removed |= 1ULL << (t4 & 63);
                        if ((t4 >> 6) == c) dm |= 1ULL << (t4 & 63);
                    }
                    if (cnt >= 6) {
                        int t5 = (int)((i1 >> 32) & 0xffffULL);
                        if (lane == (t5 >> 6)) removed |= 1ULL << (t5 & 63);
                        if ((t5 >> 6) == c) dm |= 1ULL << (t5 & 63);
                    }
                } else {
                    // rare: >6 targets -> OR in the full mask row, then
                    // refresh dm from the authoritative distributed state.
                    int r = c * 64 + b;
                    removed |= mask[(size_t)r * WORDS + (lane & 31)];
                    dm = readlane64(removed, c);
                }
            }
        }
    }

    unsigned long long keepw = 0ULL;
    if (lane < WORDS) {
        keepw = ~removed;
        int base = lane * 64;
        int valid = N - base;
        if (valid <= 0)
            keepw = 0ULL;
        else if (valid < 64)
            keepw &= ((1ULL << valid) - 1ULL);
    }

    int pc = __popcll(keepw);
    int scan = pc;
#pragma unroll
    for (int off = 1; off < 64; off <<= 1) {
        int v = __shfl_up(scan, off);
        if (lane >= off) scan += v;
    }
    int base_out = scan - pc;
    int total = __shfl(scan, WORDS - 1);

    if (lane < WORDS) {
        int pos = base_out;
        unsigned long long w = keepw;
        while (w) {
            int b = __ffsll(w) - 1;
            w &= w - 1ULL;
            if (pos < topn) out[pos] = lane * 64 + b;
            ++pos;
        }
    }
    for (int k = (total < topn ? total : topn) + lane; k < topn; k += 64)
        out[k] = -1;
}

// ---------------------------------------------------------------------------
// Kernel B (fused + inline greedy): block = row i, 256 threads.
// Phase 1: packed-AABB upper-bound filter -> LDS candidate list.
// Phase 2: fp32 clip decides unless |iou32-0.7| <= 5e-3 -> fp64 exact.
// Epilogue: mask row + rowinfo; then last-block-done (device-scope fence +
// atomic counter): the final block's first wave runs the greedy sweep.
// ---------------------------------------------------------------------------
__global__ __launch_bounds__(256) void iou_fused_kernel(
    const float4* __restrict__ aabb4, const float* __restrict__ areaf,
    const float* __restrict__ cor32, const double* __restrict__ cor,
    const double* __restrict__ areas, unsigned long long* __restrict__ mask,
    unsigned long long* __restrict__ rowinfo, unsigned int* __restrict__ done,
    int* __restrict__ out, int N, int topn) {
    __shared__ unsigned short cand[2048];
    __shared__ unsigned int lmask32[64];
    __shared__ int cnt;
    __shared__ unsigned long long nzwords;
    __shared__ int is_last;

    int i = blockIdx.x;
    int t = threadIdx.x;
    if (t == 0) cnt = 0;
    if (t < 64) lmask32[t] = 0u;
    __syncthreads();

    float4 bi = aabb4[i];
    float iaf = areaf[i];
    float thr_i = 0.699f * iaf;

    int j0 = (((i + 1) >> 8) << 8) + t;  // first 256-block containing i+1
    for (int j = j0; j < N; j += 256) {
        if (j <= i) continue;
        float4 bj = aabb4[j];
        float iw = fminf(bi.y, bj.y) - fmaxf(bi.x, bj.x);
        float ih = fminf(bi.w, bj.w) - fmaxf(bi.z, bj.z);
        if (iw > 0.0f && ih > 0.0f) {
            float jaf = areaf[j];
            float ub = fminf(iw * ih, fminf(iaf, jaf));
            if (1.699f * ub >= thr_i + 0.699f * jaf) {
                int p = atomicAdd(&cnt, 1);
                cand[p] = (unsigned short)j;
            }
        }
    }
    __syncthreads();

    int n = cnt;
    if (n) {
        float px[4], py[4];
#pragma unroll
        for (int k = 0; k < 4; ++k) {
            px[k] = cor32[i * 8 + k * 2 + 0];
            py[k] = cor32[i * 8 + k * 2 + 1];
        }
        for (int k = t; k < n; k += 256) {
            int j = (int)cand[k];
            float qx[4], qy[4];
#pragma unroll
            for (int kk = 0; kk < 4; ++kk) {
                qx[kk] = cor32[j * 8 + kk * 2 + 0];
                qy[kk] = cor32[j * 8 + kk * 2 + 1];
            }
            float inter =
                0.5f * (clip_sum_f32(px, py, qx, qy) + clip_sum_f32(qx, qy, px, py));
            inter = fmaxf(inter, 0.0f);
            float uni = iaf + areaf[j] - inter;
            float iou = inter / fmaxf(uni, 1e-8f);
            bool sup;
            if (fabsf(iou - 0.7f) > 5e-3f)
                sup = iou > 0.7f;                          // fp32 decision
            else
                sup = exact_suppress64(cor, areas, i, j);  // rare fallback
            if (sup) atomicOr(&lmask32[j >> 5], 1u << (j & 31));
        }
    }
    __syncthreads();

    if (t < 64) {
        unsigned long long bal = __ballot(lmask32[t] != 0u);
        if (t == 0) nzwords = bal;
    }
    if (t < 32) {
        unsigned long long wv = ((unsigned long long)lmask32[2 * t + 1] << 32) |
                                (unsigned long long)lmask32[2 * t];
        mask[(size_t)i * 32 + t] = wv;
    }
    __syncthreads();
    if (t == 0) {
        int total = 0, nf = 0;
        unsigned short tg[6] = {0, 0, 0, 0, 0, 0};
        unsigned long long nz = nzwords;
        while (nz) {
            int wgi = __ffsll(nz) - 1;
            nz &= nz - 1ULL;
            unsigned int v = lmask32[wgi];
            total += __popc(v);
            while (v && nf < 6) {
                int b = __ffs(v) - 1;
                v &= v - 1u;
                tg[nf++] = (unsigned short)(wgi * 32 + b);
            }
        }
        unsigned long long i0 =
            (unsigned long long)(unsigned short)total |
            ((unsigned long long)tg[0] << 16) |
            ((unsigned long long)tg[1] << 32) |
            ((unsigned long long)tg[2] << 48);
        unsigned long long i1 = (unsigned long long)tg[3] |
                                ((unsigned long long)tg[4] << 16) |
                                ((unsigned long long)tg[5] << 32);
        rowinfo[2 * i] = i0;
        rowinfo[2 * i + 1] = i1;
    }

    // ---- last-block-done: release our writes, count, last block sweeps ----
    __threadfence();  // device-scope release of mask/rowinfo stores
    if (t == 0) {
        unsigned int old = atomicAdd(done, 1u);
        is_last = (old == (unsigned int)(gridDim.x - 1));
    }
    __syncthreads();
    if (is_last) {
        __threadfence();  // acquire: see all blocks' mask/rowinfo
        if (t < 64) greedy_sweep(mask, rowinfo, out, N, topn);
    }
}

// ---------------------------------------------------------------------------
extern "C" void kernel_launch(void* const* d_in, const int* in_sizes, int n_in,
                              void* d_out, int out_size, void* d_ws,
                              size_t ws_size, hipStream_t stream) {
    const float* boxes = (const float*)d_in[0];
    int N = in_sizes[0] / 5;  // 2000 (greedy requires N <= 2048)
    int topn = out_size;      // 1000

    char* ws = (char*)d_ws;
    size_t off = 0;
    double* cor = (double*)(ws + off);     off += (size_t)N * 8 * 8;    // 128000
    float* cor32 = (float*)(ws + off);     off += (size_t)N * 8 * 4;    // 64000
    double* areas = (double*)(ws + off);   off += (size_t)N * 8;        // 16000
    unsigned long long* mask =
        (unsigned long long*)(ws + off);   off += (size_t)N * 32 * 8;   // 512000
    float4* aabb4 = (float4*)(ws + off);   off += (size_t)N * 16;       // 32000
    float* areaf = (float*)(ws + off);     off += (size_t)N * 4;        // 8000
    unsigned long long* rowinfo =
        (unsigned long long*)(ws + off);   off += (size_t)N * 16;       // 32000
    unsigned int* done = (unsigned int*)(ws + off); off += 16;

    corners_kernel<<<(N + 255) / 256, 256, 0, stream>>>(
        boxes, cor, cor32, areas, aabb4, areaf, done, N);
    iou_fused_kernel<<<N, 256, 0, stream>>>(aabb4, areaf, cor32, cor, areas,
                                            mask, rowinfo, done, (int*)d_out,
                                            N, topn);
}

// Round 10
// 84.442 us; speedup vs baseline: 2.6439x; 2.6439x over previous
//
#include <hip/hip_runtime.h>

#define NMS_TH 0.7

__device__ __forceinline__ unsigned long long readlane64(unsigned long long x,
                                                         int l) {
    unsigned int lo = __builtin_amdgcn_readlane((unsigned int)x, l);
    unsigned int hi = __builtin_amdgcn_readlane((unsigned int)(x >> 32), l);
    return ((unsigned long long)hi << 32) | lo;
}

// ---------------------------------------------------------------------------
// Kernel A: fp64 corners + fp32 corners + fp64 areas + packed fp32 AABB.
// ---------------------------------------------------------------------------
__global__ void corners_kernel(const float* __restrict__ boxes,
                               double* __restrict__ cor,    // N*8 fp64
                               float* __restrict__ cor32,   // N*8 fp32
                               double* __restrict__ areas,  // N fp64
                               float4* __restrict__ aabb4,  // N
                               float* __restrict__ areaf,   // N fp32
                               int N) {
    int i = blockIdx.x * blockDim.x + threadIdx.x;
    if (i >= N) return;
    double xc = boxes[i * 5 + 0];
    double yc = boxes[i * 5 + 1];
    double w  = boxes[i * 5 + 2];
    double h  = boxes[i * 5 + 3];
    double t  = boxes[i * 5 + 4];
    double th = t * 0.017453292519943295;  // pi/180
    double c = cos(th), s = sin(th);
    const double lx[4] = {0.5, -0.5, -0.5, 0.5};
    const double ly[4] = {0.5, 0.5, -0.5, -0.5};
    double xmn = 1e30, xmx = -1e30, ymn = 1e30, ymx = -1e30;
#pragma unroll
    for (int k = 0; k < 4; ++k) {
        double x = xc + lx[k] * w * c - ly[k] * h * s;
        double y = yc + lx[k] * w * s + ly[k] * h * c;
        cor[i * 8 + k * 2 + 0] = x;
        cor[i * 8 + k * 2 + 1] = y;
        cor32[i * 8 + k * 2 + 0] = (float)x;
        cor32[i * 8 + k * 2 + 1] = (float)y;
        xmn = fmin(xmn, x); xmx = fmax(xmx, x);
        ymn = fmin(ymn, y); ymx = fmax(ymx, y);
    }
    areas[i] = w * h;
    aabb4[i] = make_float4((float)xmn, (float)xmx, (float)ymn, (float)ymx);
    areaf[i] = (float)(w * h);
}

// ---------------------------------------------------------------------------
// Convex-quad intersection area via Green's theorem — fp64 exact version.
// ---------------------------------------------------------------------------
__device__ __forceinline__ double clip_sum(const double* __restrict__ px,
                                           const double* __restrict__ py,
                                           const double* __restrict__ qx,
                                           const double* __restrict__ qy) {
    double acc = 0.0;
#pragma unroll
    for (int e = 0; e < 4; ++e) {
        double x0 = px[e], y0 = py[e];
        double x1 = px[(e + 1) & 3], y1 = py[(e + 1) & 3];
        double dx = x1 - x0, dy = y1 - y0;
        double t0 = 0.0, t1 = 1.0;
        bool empty = false;
#pragma unroll
        for (int f = 0; f < 4; ++f) {
            double ex0 = qx[f], ey0 = qy[f];
            double ex1 = qx[(f + 1) & 3], ey1 = qy[(f + 1) & 3];
            double edx = ex1 - ex0, edy = ey1 - ey0;
            double f0 = edx * (y0 - ey0) - edy * (x0 - ex0);
            double f1 = edx * (y1 - ey0) - edy * (x1 - ex0);
            double df = f1 - f0;
            if (df > 0.0) {
                t0 = fmax(t0, -f0 / df);
            } else if (df < 0.0) {
                t1 = fmin(t1, -f0 / df);
            } else if (f0 < 0.0) {
                empty = true;
            }
        }
        if (!empty && t0 < t1) {
            double ax = x0 + t0 * dx, ay = y0 + t0 * dy;
            double bx = x0 + t1 * dx, by = y0 + t1 * dy;
            acc += ax * by - bx * ay;
        }
    }
    return acc;
}

__device__ __forceinline__ bool exact_suppress64(const double* __restrict__ cor,
                                                 const double* __restrict__ areas,
                                                 int i, int j) {
    double px[4], py[4], qx[4], qy[4];
#pragma unroll
    for (int k = 0; k < 4; ++k) {
        px[k] = cor[i * 8 + k * 2 + 0];
        py[k] = cor[i * 8 + k * 2 + 1];
        qx[k] = cor[j * 8 + k * 2 + 0];
        qy[k] = cor[j * 8 + k * 2 + 1];
    }
    double inter = 0.5 * (clip_sum(px, py, qx, qy) + clip_sum(qx, qy, px, py));
    inter = fmax(inter, 0.0);
    double uni = areas[i] + areas[j] - inter;
    double iou = inter / fmax(uni, 1e-8);
    return iou > NMS_TH;
}

// ---------------------------------------------------------------------------
// fp32 fast-path clip (hardware rcp, ~1 ulp — inside the decision band).
// ---------------------------------------------------------------------------
__device__ __forceinline__ float clip_sum_f32(const float* __restrict__ px,
                                              const float* __restrict__ py,
                                              const float* __restrict__ qx,
                                              const float* __restrict__ qy) {
    float acc = 0.0f;
#pragma unroll
    for (int e = 0; e < 4; ++e) {
        float x0 = px[e], y0 = py[e];
        float x1 = px[(e + 1) & 3], y1 = py[(e + 1) & 3];
        float dx = x1 - x0, dy = y1 - y0;
        float t0 = 0.0f, t1 = 1.0f;
        bool empty = false;
#pragma unroll
        for (int f = 0; f < 4; ++f) {
            float ex0 = qx[f], ey0 = qy[f];
            float ex1 = qx[(f + 1) & 3], ey1 = qy[(f + 1) & 3];
            float edx = ex1 - ex0, edy = ey1 - ey0;
            float f0 = edx * (y0 - ey0) - edy * (x0 - ex0);
            float f1 = edx * (y1 - ey0) - edy * (x1 - ex0);
            float df = f1 - f0;
            if (df > 0.0f) {
                t0 = fmaxf(t0, -f0 * __builtin_amdgcn_rcpf(df));
            } else if (df < 0.0f) {
                t1 = fminf(t1, -f0 * __builtin_amdgcn_rcpf(df));
            } else if (f0 < 0.0f) {
                empty = true;
            }
        }
        if (!empty && t0 < t1) {
            float ax = x0 + t0 * dx, ay = y0 + t0 * dy;
            float bx = x0 + t1 * dx, by = y0 + t1 * dy;
            acc += ax * by - bx * ay;
        }
    }
    return acc;
}

// ---------------------------------------------------------------------------
// Kernel B (fused): block = row i, 256 threads.
// Phase 1: packed-AABB upper-bound filter (exact-safe guard band) -> LDS
//   candidate list.
// Phase 2: fp32 clip decides unless |iou32-0.7| <= 5e-3, then fp64 exact.
// Epilogue: 32-word mask row + rowinfo (count + first 6 targets inline).
// NOTE (R9 lesson): do NOT fuse the greedy sweep in here — its register
// arrays spill to scratch in a 256-thread kernel context (76 VGPR, scratch
// chain -> 170 µs single-wave crawl).  Separate 64-thread kernel registerizes.
// ---------------------------------------------------------------------------
__global__ __launch_bounds__(256) void iou_fused_kernel(
    const float4* __restrict__ aabb4, const float* __restrict__ areaf,
    const float* __restrict__ cor32, const double* __restrict__ cor,
    const double* __restrict__ areas, unsigned long long* __restrict__ mask,
    unsigned long long* __restrict__ rowinfo, int N) {
    __shared__ unsigned short cand[2048];
    __shared__ unsigned int lmask32[64];
    __shared__ int cnt;
    __shared__ unsigned long long nzwords;

    int i = blockIdx.x;
    int t = threadIdx.x;
    if (t == 0) cnt = 0;
    if (t < 64) lmask32[t] = 0u;
    __syncthreads();

    float4 bi = aabb4[i];
    float iaf = areaf[i];
    float thr_i = 0.699f * iaf;

    int j0 = (((i + 1) >> 8) << 8) + t;  // first 256-block containing i+1
    for (int j = j0; j < N; j += 256) {
        if (j <= i) continue;
        float4 bj = aabb4[j];
        float iw = fminf(bi.y, bj.y) - fmaxf(bi.x, bj.x);
        float ih = fminf(bi.w, bj.w) - fmaxf(bi.z, bj.z);
        if (iw > 0.0f && ih > 0.0f) {
            float jaf = areaf[j];
            float ub = fminf(iw * ih, fminf(iaf, jaf));
            if (1.699f * ub >= thr_i + 0.699f * jaf) {
                int p = atomicAdd(&cnt, 1);
                cand[p] = (unsigned short)j;
            }
        }
    }
    __syncthreads();

    int n = cnt;
    if (n) {
        float px[4], py[4];
#pragma unroll
        for (int k = 0; k < 4; ++k) {
            px[k] = cor32[i * 8 + k * 2 + 0];
            py[k] = cor32[i * 8 + k * 2 + 1];
        }
        for (int k = t; k < n; k += 256) {
            int j = (int)cand[k];
            float qx[4], qy[4];
#pragma unroll
            for (int kk = 0; kk < 4; ++kk) {
                qx[kk] = cor32[j * 8 + kk * 2 + 0];
                qy[kk] = cor32[j * 8 + kk * 2 + 1];
            }
            float inter =
                0.5f * (clip_sum_f32(px, py, qx, qy) + clip_sum_f32(qx, qy, px, py));
            inter = fmaxf(inter, 0.0f);
            float uni = iaf + areaf[j] - inter;
            float iou = inter / fmaxf(uni, 1e-8f);
            bool sup;
            if (fabsf(iou - 0.7f) > 5e-3f)
                sup = iou > 0.7f;                          // fp32 decision
            else
                sup = exact_suppress64(cor, areas, i, j);  // rare fallback
            if (sup) atomicOr(&lmask32[j >> 5], 1u << (j & 31));
        }
    }
    __syncthreads();

    if (t < 64) {
        unsigned long long bal = __ballot(lmask32[t] != 0u);
        if (t == 0) nzwords = bal;
    }
    if (t < 32) {
        unsigned long long wv = ((unsigned long long)lmask32[2 * t + 1] << 32) |
                                (unsigned long long)lmask32[2 * t];
        mask[(size_t)i * 32 + t] = wv;
    }
    __syncthreads();
    if (t == 0) {
        int total = 0, nf = 0;
        unsigned short tg[6] = {0, 0, 0, 0, 0, 0};
        unsigned long long nz = nzwords;
        while (nz) {
            int wgi = __ffsll(nz) - 1;
            nz &= nz - 1ULL;
            unsigned int v = lmask32[wgi];
            total += __popc(v);
            while (v && nf < 6) {
                int b = __ffs(v) - 1;
                v &= v - 1u;
                tg[nf++] = (unsigned short)(wgi * 32 + b);
            }
        }
        unsigned long long i0 =
            (unsigned long long)(unsigned short)total |
            ((unsigned long long)tg[0] << 16) |
            ((unsigned long long)tg[1] << 32) |
            ((unsigned long long)tg[2] << 48);
        unsigned long long i1 = (unsigned long long)tg[3] |
                                ((unsigned long long)tg[4] << 16) |
                                ((unsigned long long)tg[5] << 32);
        rowinfo[2 * i] = i0;
        rowinfo[2 * i + 1] = i1;
    }
}

// ---------------------------------------------------------------------------
// Kernel C: edge-list greedy sweep, one wave (standalone 64-thread kernel so
// the ri0/ri1 arrays REGISTERIZE — R9 showed they spill to scratch in a
// 256-thread fused context).  Lane l (<32) owns 'removed' word l.  dm (the
// current chunk's removed word) is maintained in scalar registers: inline
// targets update it directly; readlane64 refresh only in the rare cnt>6
// mask-row fallback.  Requires N <= 2048; mask stride fixed at 32 words.
// ---------------------------------------------------------------------------
__global__ __launch_bounds__(64, 1) void greedy_kernel(
    const unsigned long long* __restrict__ mask,
    const unsigned long long* __restrict__ rowinfo, int* __restrict__ out,
    int N, int topn) {
    constexpr int WORDS = 32;
    int lane = threadIdx.x;
    unsigned long long removed = 0ULL;

    unsigned long long ri0[WORDS], ri1[WORDS];
    const ulonglong2* rv = (const ulonglong2*)rowinfo;
#pragma unroll
    for (int c = 0; c < WORDS; ++c) {
        int r = c * 64 + lane;
        if (r < N) {
            ulonglong2 v = rv[r];
            ri0[c] = v.x;
            ri1[c] = v.y;
        } else {
            ri0[c] = 0ULL;
            ri1[c] = 0ULL;
        }
    }

#pragma unroll
    for (int c = 0; c < WORDS; ++c) {
        unsigned long long bits = __ballot((ri0[c] & 0xffffULL) != 0ULL);
        if (!bits) continue;
        unsigned long long dm = readlane64(removed, c);  // scalar copy
        unsigned long long todo = bits;
        for (;;) {
            unsigned long long bb = todo & ~dm;
            if (!bb) break;
            int b = __builtin_amdgcn_readfirstlane(__ffsll(bb) - 1);
            todo &= ~(1ULL << b);
            unsigned long long i0 = readlane64(ri0[c], b);
            int cnt = (int)(i0 & 0xffffULL);
            {
                int t0 = (int)((i0 >> 16) & 0xffffULL);
                if (lane == (t0 >> 6)) removed |= 1ULL << (t0 & 63);
                if ((t0 >> 6) == c) dm |= 1ULL << (t0 & 63);
            }
            if (cnt >= 2) {
                int t1 = (int)((i0 >> 32) & 0xffffULL);
                if (lane == (t1 >> 6)) removed |= 1ULL << (t1 & 63);
                if ((t1 >> 6) == c) dm |= 1ULL << (t1 & 63);
            }
            if (cnt >= 3) {
                int t2 = (int)((i0 >> 48) & 0xffffULL);
                if (lane == (t2 >> 6)) removed |= 1ULL << (t2 & 63);
                if ((t2 >> 6) == c) dm |= 1ULL << (t2 & 63);
            }
            if (cnt >= 4) {
                if (cnt <= 6) {
                    unsigned long long i1 = readlane64(ri1[c], b);
                    int t3 = (int)(i1 & 0xffffULL);
                    if (lane == (t3 >> 6)) removed |= 1ULL << (t3 & 63);
                    if ((t3 >> 6) == c) dm |= 1ULL << (t3 & 63);
                    if (cnt >= 5) {
                        int t4 = (int)((i1 >> 16) & 0xffffULL);
                        if (lane == (t4 >> 6)) removed |= 1ULL << (t4 & 63);
                        if ((t4 >> 6) == c) dm |= 1ULL << (t4 & 63);
                    }
                    if (cnt >= 6) {
                        int t5 = (int)((i1 >> 32) & 0xffffULL);
                        if (lane == (t5 >> 6)) removed |= 1ULL << (t5 & 63);
                        if ((t5 >> 6) == c) dm |= 1ULL << (t5 & 63);
                    }
                } else {
                    // rare: >6 targets -> OR in the full mask row, then
                    // refresh dm from the authoritative distributed state.
                    int r = c * 64 + b;
                    removed |= mask[(size_t)r * WORDS + (lane & 31)];
                    dm = readlane64(removed, c);
                }
            }
        }
    }

    unsigned long long keepw = 0ULL;
    if (lane < WORDS) {
        keepw = ~removed;
        int base = lane * 64;
        int valid = N - base;
        if (valid <= 0)
            keepw = 0ULL;
        else if (valid < 64)
            keepw &= ((1ULL << valid) - 1ULL);
    }

    int pc = __popcll(keepw);
    int scan = pc;
#pragma unroll
    for (int off = 1; off < 64; off <<= 1) {
        int v = __shfl_up(scan, off);
        if (lane >= off) scan += v;
    }
    int base_out = scan - pc;
    int total = __shfl(scan, WORDS - 1);

    if (lane < WORDS) {
        int pos = base_out;
        unsigned long long w = keepw;
        while (w) {
            int b = __ffsll(w) - 1;
            w &= w - 1ULL;
            if (pos < topn) out[pos] = lane * 64 + b;
            ++pos;
        }
    }
    for (int k = (total < topn ? total : topn) + lane; k < topn; k += 64)
        out[k] = -1;
}

// ---------------------------------------------------------------------------
extern "C" void kernel_launch(void* const* d_in, const int* in_sizes, int n_in,
                              void* d_out, int out_size, void* d_ws,
                              size_t ws_size, hipStream_t stream) {
    const float* boxes = (const float*)d_in[0];
    int N = in_sizes[0] / 5;  // 2000 (greedy requires N <= 2048)
    int topn = out_size;      // 1000

    char* ws = (char*)d_ws;
    size_t off = 0;
    double* cor = (double*)(ws + off);     off += (size_t)N * 8 * 8;    // 128000
    float* cor32 = (float*)(ws + off);     off += (size_t)N * 8 * 4;    // 64000
    double* areas = (double*)(ws + off);   off += (size_t)N * 8;        // 16000
    unsigned long long* mask =
        (unsigned long long*)(ws + off);   off += (size_t)N * 32 * 8;   // 512000
    float4* aabb4 = (float4*)(ws + off);   off += (size_t)N * 16;       // 32000
    float* areaf = (float*)(ws + off);     off += (size_t)N * 4;        // 8000
    unsigned long long* rowinfo =
        (unsigned long long*)(ws + off);   off += (size_t)N * 16;       // 32000

    corners_kernel<<<(N + 255) / 256, 256, 0, stream>>>(
        boxes, cor, cor32, areas, aabb4, areaf, N);
    iou_fused_kernel<<<N, 256, 0, stream>>>(aabb4, areaf, cor32, cor, areas,
                                            mask, rowinfo, N);
    greedy_kernel<<<1, 64, 0, stream>>>(mask, rowinfo, (int*)d_out, N, topn);
}